// Round 1
// baseline (3443.713 us; speedup 1.0000x reference)
//
#include <hip/hip_runtime.h>
#include <hip/hip_bf16.h>
#include <hip/hip_fp16.h>

// Problem: S,B,E,H,V,O = 1024,256,128,256,32000,2
#define S_LEN 1024
#define BATCH 256
#define EDIM  128
#define HDIM  256
#define ODIM  2

typedef unsigned int uint32;
typedef unsigned long long uint64;
typedef _Float16 half_t;
typedef half_t half2v __attribute__((ext_vector_type(2)));
typedef half_t half8  __attribute__((ext_vector_type(8)));
typedef float  f32x4  __attribute__((ext_vector_type(4)));

// ---------------- ws layout (uint32 units) ----------------
// whhf: MFMA A-fragments of W_hh, [4 q][16 T][8 t][64 lane][4 dw]  (f16 pairs)
// wihf: MFMA A-fragments of W_ih, [4 q][16 T][4 t][64 lane][4 dw]
// hbuf: LL-style chunks: [2 par][16 c][16 b][128 dw] x {payload dw, seq dw}
//       payload dw d of col b = halves h[2d], h[2d+1]; seq = s+1 (monotone).
//       8B atomic store => payload+seq visible together; sc1 write-through
//       => deterministic cross-CU visibility (no eviction dependence).
#define OFF_WHHF   0
#define OFF_WIHF   131072
#define OFF_HBUF   196608
#define HBUF_DW    131072   // 65536 chunks * 2 dw

__device__ __forceinline__ float sigf(float x)     { return 1.0f / (1.0f + __expf(-x)); }
__device__ __forceinline__ float tanhfast(float x) { return 1.0f - 2.0f / (__expf(2.0f * x) + 1.0f); }

__device__ __forceinline__ uint32 packh2(float a, float b) {
  union { uint32 u; half2v h; } c; c.h[0] = (half_t)a; c.h[1] = (half_t)b; return c.u;
}
__device__ __forceinline__ half8 as_h8(uint4 v) {
  union { uint4 u; half8 h; } c; c.u = v; return c.h;
}

// ---------------- prep: pack W into per-lane MFMA A-fragment order ----------------
// A-layout (16x16x32): lane l holds A[m = l&15][k = (l>>4)*8 + j], j=0..7 (f16 pairs in 4 dwords).
// Block q owns hidden units 64q..64q+63; tile T: gate g=T>>2, unit sub-block T&3.
// grow(T,l) = (T>>2)*256 + q*64 + (T&3)*16 + (l&15).
__global__ void prep_kernel(const float* __restrict__ w_ih, const float* __restrict__ w_hh,
                            uint32* __restrict__ ws_u) {
  int id = blockIdx.x * 256 + threadIdx.x;
  if (id < 131072) {                     // whhf dwords: [q][T][t(8)][l][d]
    int q = id >> 15, T = (id >> 11) & 15, t = (id >> 8) & 7, l = (id >> 2) & 63, d = id & 3;
    int grow = (T >> 2) * 256 + q * 64 + (T & 3) * 16 + (l & 15);
    int k = t * 32 + (l >> 4) * 8 + 2 * d;
    ws_u[OFF_WHHF + id] = packh2(w_hh[grow * HDIM + k], w_hh[grow * HDIM + k + 1]);
  } else if (id < 131072 + 65536) {      // wihf dwords: [q][T][t(4)][l][d]
    int i2 = id - 131072;
    int q = i2 >> 14, T = (i2 >> 10) & 15, t = (i2 >> 8) & 3, l = (i2 >> 2) & 63, d = i2 & 3;
    int grow = (T >> 2) * 256 + q * 64 + (T & 3) * 16 + (l & 15);
    int k = t * 32 + (l >> 4) * 8 + 2 * d;
    ws_u[OFF_WIHF + i2] = packh2(w_ih[grow * EDIM + k], w_ih[grow * EDIM + k + 1]);
  } else if (id < 131072 + 65536 + HBUF_DW) {
    ws_u[OFF_HBUF + (id - 131072 - 65536)] = 0;   // zero seqs (and payloads)
  }
}

// ---------------- LSTM: MFMA recurrence, LL-seqlock h-exchange ----------------
// 16 clusters x 4 members = 64 blocks. Cluster c: batch cols 16c..16c+15.
// Member q = bid>>4: hidden units 64q..64q+63 (gate rows g*256+64q+[0,64)).
// 512 threads = 8 waves; wave w owns row-tiles T=2w,2w+1; weights in VGPRs.
// Flow control: chunk at parity P, written at step s (seq s+1), is next
// overwritten at s+2 — which happens-after this writer validated all peers'
// seq s+2 publishes, which happen-after those peers consumed this chunk.
// So observed seq is always <= expected; spin on (seq < s) is safe.
__global__ __launch_bounds__(512, 2) void lstm_kernel(
    const int* __restrict__ inp, const int* __restrict__ lengths,
    const float* __restrict__ h0, const float* __restrict__ c0,
    const float* __restrict__ emb,
    const float* __restrict__ b_ih, const float* __restrict__ b_hh,
    uint32* __restrict__ ws_u,
    float* __restrict__ outh, float* __restrict__ outc) {
  __shared__ uint32 x_l[2 * 16 * 68];   // [parity][b][64 dw + pad4]  x as f16 pairs
  __shared__ uint32 h_l[16 * 132];      // [b][128 dw + pad4]         h as f16 pairs
  __shared__ float  gbuf[16 * 16 * 20]; // [T][row16][16 cols + pad4] fp32 gates

  const int tid  = threadIdx.x;
  const int lane = tid & 63, w = tid >> 6;
  const int c = blockIdx.x & 15, q = blockIdx.x >> 4;
  const int n = lane & 15, p = lane >> 4;   // MFMA col / quad
  const int sb = tid >> 5, sk = tid & 31;   // staging map: col/token sb, group sk
  const int up = tid >> 4, b = tid & 15;    // epilogue map: unit-pair up, col b
  const bool stage_on = ((sk >> 3) != q);   // skip own member's dw range [32q,32q+32)

  uint64* hb = (uint64*)(ws_u + OFF_HBUF);

  // ---- load weight A-fragments into registers (persistent) ----
  uint4 ahh[2][8], aih[2][4];
  {
    const uint4* whhf = (const uint4*)(ws_u + OFF_WHHF);
    const uint4* wihf = (const uint4*)(ws_u + OFF_WIHF);
#pragma unroll
    for (int T2 = 0; T2 < 2; ++T2) {
      int T = 2 * w + T2;
#pragma unroll
      for (int t = 0; t < 8; ++t) ahh[T2][t] = whhf[((q * 16 + T) * 8 + t) * 64 + lane];
#pragma unroll
      for (int t = 0; t < 4; ++t) aih[T2][t] = wihf[((q * 16 + T) * 4 + t) * 64 + lane];
    }
  }

  // ---- per-thread epilogue state: units u=2up, 2up+1 of member q; col b ----
  float bias_[2][4], cst[2];
  const int len = lengths[16 * c + b] - 1;
#pragma unroll
  for (int e = 0; e < 2; ++e) {
    int u = 2 * up + e;
#pragma unroll
    for (int g = 0; g < 4; ++g) {
      int grow = g * 256 + q * 64 + u;
      bias_[e][g] = b_ih[grow] + b_hh[grow];
    }
    cst[e] = c0[(16 * c + b) * HDIM + q * 64 + u];
  }

  // ---- prologue staging: h0 -> h_l (full), x_0 -> x_l[0] ----
  {
    const float4* s0 = (const float4*)(h0 + (16 * c + sb) * HDIM) + 2 * sk;
    float4 a0 = s0[0], a1 = s0[1];
    uint4 pk = { packh2(a0.x, a0.y), packh2(a0.z, a0.w), packh2(a1.x, a1.y), packh2(a1.z, a1.w) };
    *(uint4*)(h_l + sb * 132 + 4 * sk) = pk;
    int tok = inp[16 * c + sb];
    float4 v = ((const float4*)(emb + tok * EDIM))[sk];
    uint2 px = { packh2(v.x, v.y), packh2(v.z, v.w) };
    *(uint2*)(x_l + sb * 68 + 2 * sk) = px;
  }
  __syncthreads();

  for (int s = 0; s < S_LEN; ++s) {
    const int par = s & 1;

    // ---- C-issue: speculative chunk loads of peers' h_{s-1} (validated later) ----
    uint64 h0v = 0, h1v = 0, h2v = 0, h3v = 0;
    const uint64* rp = hb + ((((par ^ 1) * 16 + c) * 16 + sb) * 128 + 4 * sk);
    const bool do_stage = (s > 0) && stage_on;
    if (do_stage) {
      h0v = __hip_atomic_load(rp + 0, __ATOMIC_RELAXED, __HIP_MEMORY_SCOPE_AGENT);
      h1v = __hip_atomic_load(rp + 1, __ATOMIC_RELAXED, __HIP_MEMORY_SCOPE_AGENT);
      h2v = __hip_atomic_load(rp + 2, __ATOMIC_RELAXED, __HIP_MEMORY_SCOPE_AGENT);
      h3v = __hip_atomic_load(rp + 3, __ATOMIC_RELAXED, __HIP_MEMORY_SCOPE_AGENT);
    }

    // ---- B: x-part MFMA (covers chunk-load latency) ----
    f32x4 acc0 = {0.f, 0.f, 0.f, 0.f}, acc1 = {0.f, 0.f, 0.f, 0.f};
#pragma unroll
    for (int t = 0; t < 4; ++t) {
      uint4 xb = *(const uint4*)(x_l + par * 1088 + n * 68 + t * 16 + p * 4);
      acc0 = __builtin_amdgcn_mfma_f32_16x16x32_f16(as_h8(aih[0][t]), as_h8(xb), acc0, 0, 0, 0);
      acc1 = __builtin_amdgcn_mfma_f32_16x16x32_f16(as_h8(aih[1][t]), as_h8(xb), acc1, 0, 0, 0);
    }

    // ---- C-check: validate seqs, spin-reload only if stale; stage into h_l ----
    if (do_stage) {
      const uint32 us = (uint32)s;
      while (((uint32)(h0v >> 32) < us) | ((uint32)(h1v >> 32) < us) |
             ((uint32)(h2v >> 32) < us) | ((uint32)(h3v >> 32) < us)) {
        h0v = __hip_atomic_load(rp + 0, __ATOMIC_RELAXED, __HIP_MEMORY_SCOPE_AGENT);
        h1v = __hip_atomic_load(rp + 1, __ATOMIC_RELAXED, __HIP_MEMORY_SCOPE_AGENT);
        h2v = __hip_atomic_load(rp + 2, __ATOMIC_RELAXED, __HIP_MEMORY_SCOPE_AGENT);
        h3v = __hip_atomic_load(rp + 3, __ATOMIC_RELAXED, __HIP_MEMORY_SCOPE_AGENT);
      }
      uint4 pk = { (uint32)h0v, (uint32)h1v, (uint32)h2v, (uint32)h3v };
      *(uint4*)(h_l + sb * 132 + 4 * sk) = pk;
    }
    __syncthreads();   // B2: h_l complete

    // ---- A: issue emb gather for x_{s+1} AFTER staging (no vmcnt interference
    //      with the spin); consumed ~500cy later at G (T14 issue-early/use-late) ----
    float4 xv = {0.f, 0.f, 0.f, 0.f};
    if (s + 1 < S_LEN) {
      int tok = inp[(s + 1) * BATCH + 16 * c + sb];
      xv = ((const float4*)(emb + tok * EDIM))[sk];
    }

    // ---- D: h-part MFMA ----
#pragma unroll
    for (int t = 0; t < 8; ++t) {
      uint4 hbv = *(const uint4*)(h_l + n * 132 + t * 16 + p * 4);
      acc0 = __builtin_amdgcn_mfma_f32_16x16x32_f16(as_h8(ahh[0][t]), as_h8(hbv), acc0, 0, 0, 0);
      acc1 = __builtin_amdgcn_mfma_f32_16x16x32_f16(as_h8(ahh[1][t]), as_h8(hbv), acc1, 0, 0, 0);
    }

    // ---- E: C -> gbuf (D layout: row = p*4+r, col = n) ----
#pragma unroll
    for (int r = 0; r < 4; ++r) {
      gbuf[(2 * w) * 320 + (p * 4 + r) * 20 + n]     = acc0[r];
      gbuf[(2 * w + 1) * 320 + (p * 4 + r) * 20 + n] = acc1[r];
    }
    __syncthreads();   // B3

    // ---- F: gate math, c/h update for units 2up, 2up+1 ----
    float hn2[2];
#pragma unroll
    for (int e = 0; e < 2; ++e) {
      int u = 2 * up + e, Tb = u >> 4, ur = u & 15;
      float gi = gbuf[(0  + Tb) * 320 + ur * 20 + b] + bias_[e][0];
      float gf = gbuf[(4  + Tb) * 320 + ur * 20 + b] + bias_[e][1];
      float gg = gbuf[(8  + Tb) * 320 + ur * 20 + b] + bias_[e][2];
      float go = gbuf[(12 + Tb) * 320 + ur * 20 + b] + bias_[e][3];
      float iv = sigf(gi), fv = sigf(gf), gv = tanhfast(gg), ov = sigf(go);
      float cn = fv * cst[e] + iv * gv;
      cst[e] = cn;
      float hv = ov * tanhfast(cn);
      hn2[e] = hv;
      if (s == len) {
        outh[(16 * c + b) * HDIM + q * 64 + u] = hv;
        outc[(16 * c + b) * HDIM + q * 64 + u] = cn;
      }
    }

    // ---- G: publish chunk (single 8B atomic, payload+seq together), own-slice
    //      shortcut into h_l, and x_{s+1} -> x_l[par^1] (emb latency elapsed) ----
    if (s + 1 < S_LEN) {
      uint32 pay = packh2(hn2[0], hn2[1]);
      uint64 pv = (uint64)pay | ((uint64)(uint32)(s + 1) << 32);
      __hip_atomic_store(hb + (((par * 16 + c) * 16 + b) * 128 + q * 32 + up), pv,
                         __ATOMIC_RELAXED, __HIP_MEMORY_SCOPE_AGENT);
      h_l[b * 132 + q * 32 + up] = pay;
      uint2 px = { packh2(xv.x, xv.y), packh2(xv.z, xv.w) };
      *(uint2*)(x_l + (par ^ 1) * 1088 + sb * 68 + 2 * sk) = px;
    }
    __syncthreads();   // B4: x_l/h_l own-writes visible to next step
  }
}

// ---------------- decode: [B,2] = sigmoid(last_h @ dec_w^T) ----------------
__global__ __launch_bounds__(64) void decode_kernel(const float* __restrict__ outh,
                                                    const float* __restrict__ dec_w,
                                                    float* __restrict__ dec) {
  int b = blockIdx.x, l = threadIdx.x;
  float p0 = 0.f, p1 = 0.f;
#pragma unroll
  for (int m = 0; m < HDIM / 64; ++m) {
    float h = outh[b * HDIM + l + 64 * m];
    p0 = fmaf(h, dec_w[l + 64 * m], p0);
    p1 = fmaf(h, dec_w[HDIM + l + 64 * m], p1);
  }
#pragma unroll
  for (int off = 32; off > 0; off >>= 1) {
    p0 += __shfl_down(p0, off);
    p1 += __shfl_down(p1, off);
  }
  if (l == 0) {
    dec[b * ODIM + 0] = sigf(p0);
    dec[b * ODIM + 1] = sigf(p1);
  }
}

extern "C" void kernel_launch(void* const* d_in, const int* in_sizes, int n_in,
                              void* d_out, int out_size, void* d_ws, size_t ws_size,
                              hipStream_t stream) {
  const int*   inp     = (const int*)d_in[0];
  const int*   lengths = (const int*)d_in[1];
  const float* h0      = (const float*)d_in[2];
  const float* c0      = (const float*)d_in[3];
  const float* emb     = (const float*)d_in[4];
  const float* w_ih    = (const float*)d_in[5];
  const float* w_hh    = (const float*)d_in[6];
  const float* b_ih    = (const float*)d_in[7];
  const float* b_hh    = (const float*)d_in[8];
  const float* dec_w   = (const float*)d_in[9];

  uint32* ws_u = (uint32*)d_ws;

  float* dec  = (float*)d_out;           // [B, 2]
  float* outh = dec + BATCH * ODIM;      // [1, B, H]
  float* outc = outh + BATCH * HDIM;     // [1, B, H]

  const int prep_total = 131072 + 65536 + HBUF_DW;
  prep_kernel<<<(prep_total + 255) / 256, 256, 0, stream>>>(w_ih, w_hh, ws_u);
  lstm_kernel<<<64, 512, 0, stream>>>(inp, lengths, h0, c0, emb, b_ih, b_hh,
                                      ws_u, outh, outc);
  decode_kernel<<<BATCH, 64, 0, stream>>>(outh, dec_w, dec);
}